// Round 1
// baseline (1391.893 us; speedup 1.0000x reference)
//
#include <hip/hip_runtime.h>

// PagedAttention fused pipeline for MI355X (gfx950).
// B=4 S=4096 HID=2048 H=16 P=256 D=128 N=16.
// Paged permutation (derived from flat strides of the unfold/reshape):
//   q/k/v:  heads[b,h,n*P+p,d] -> paged[x2=16b+h][h2=n][p2=2d+(p>>7)][d2=p&127]
//   output: ctx[x2][h2][p2][d3] -> out[b=x2>>4][s=256*(x2&15)+p2][c=128*h2+d3]
// Pipeline: cvt fp32->bf16; QKV GEMMs (write paged / transposed-paged bf16);
// per-page MFMA attention (S^T orientation, register-only); out-proj GEMM (fp32 out).

typedef unsigned short u16;
typedef unsigned int u32;
typedef __attribute__((ext_vector_type(8))) __bf16 bf16x8;
typedef __attribute__((ext_vector_type(4))) float f32x4;
typedef __attribute__((ext_vector_type(8))) u16 u16x8;

struct alignas(8) U4 { u16 x, y, z, w; };

#define SCALE_ 0.08838834764831845f

__device__ __forceinline__ u16 f2bf(float f) {
  union { float f; u32 u; } v; v.f = f;
  u32 r = v.u + 0x7fffu + ((v.u >> 16) & 1u);   // RNE
  return (u16)(r >> 16);
}

__device__ __forceinline__ void glds16(const void* g, void* l) {
  __builtin_amdgcn_global_load_lds(
      (const __attribute__((address_space(1))) u32*)g,
      (__attribute__((address_space(3))) u32*)l, 16, 0, 0);
}

// ---------------- fp32 -> bf16 conversion (vectorized x4) ----------------
__global__ void cvt_kernel(const float* __restrict__ src, u16* __restrict__ dst, int n4) {
  int i = blockIdx.x * 256 + threadIdx.x;
  if (i >= n4) return;
  float4 f = ((const float4*)src)[i];
  U4 o = { f2bf(f.x), f2bf(f.y), f2bf(f.z), f2bf(f.w) };
  ((U4*)dst)[i] = o;
}

// ---------------- GEMM: C[m,n] = sum_k A[m,k]*W[n,k] + bias[n] ----------------
// 128x128 tile, BK=32, 4 waves (2x2 of 64x64), global_load_lds staging.
// mode 0: write bf16 paged layout (Q/K).  mode 1: write bf16 transposed-paged (V).
// mode 2: write fp32 row-major (final output).
__global__ __launch_bounds__(256) void gemm_kernel(
    const u16* __restrict__ A, const u16* __restrict__ Bw,
    const float* __restrict__ bias, void* __restrict__ outp, int mode)
{
  __shared__ u16 As[128 * 32];
  __shared__ u16 Bs[128 * 32];
  const int tid  = threadIdx.x;
  const int wid  = tid >> 6;
  const int lane = tid & 63;
  const int L    = lane & 15;
  const int quad = lane >> 4;
  const int m0 = blockIdx.y << 7;
  const int n0 = blockIdx.x << 7;
  const int wm = (wid >> 1) << 6;
  const int wn = (wid & 1) << 6;

  f32x4 acc[4][4];
#pragma unroll
  for (int i = 0; i < 4; ++i)
#pragma unroll
    for (int j = 0; j < 4; ++j)
      acc[i][j] = f32x4{0.f, 0.f, 0.f, 0.f};

  for (int kk = 0; kk < 2048; kk += 32) {
#pragma unroll
    for (int r = 0; r < 2; ++r) {
      const int unit = tid + (r << 8);          // 0..511, 16B units
      const int row  = unit >> 2;               // 0..127
      const int su   = unit & 3;                // 0..3 (8 bf16 each)
      glds16(A  + (size_t)(m0 + row) * 2048 + kk + su * 8, (char*)As + unit * 16);
      glds16(Bw + (size_t)(n0 + row) * 2048 + kk + su * 8, (char*)Bs + unit * 16);
    }
    __syncthreads();
    bf16x8 af[4], bfr[4];
#pragma unroll
    for (int t = 0; t < 4; ++t) {
      af[t]  = *(const bf16x8*)((const char*)As + (wm + t * 16 + L) * 64 + quad * 16);
      bfr[t] = *(const bf16x8*)((const char*)Bs + (wn + t * 16 + L) * 64 + quad * 16);
    }
#pragma unroll
    for (int mt = 0; mt < 4; ++mt)
#pragma unroll
      for (int nt = 0; nt < 4; ++nt)
        acc[mt][nt] = __builtin_amdgcn_mfma_f32_16x16x32_bf16(af[mt], bfr[nt], acc[mt][nt], 0, 0, 0);
    __syncthreads();
  }

  // Epilogue. C frag: col = lane&15 (n), rows = quad*4 + reg (m).
#pragma unroll
  for (int nt = 0; nt < 4; ++nt) {
    const int c = n0 + wn + nt * 16 + L;
    const float bv = bias[c];
    const int h = c >> 7, d = c & 127;
#pragma unroll
    for (int mt = 0; mt < 4; ++mt) {
      const int rit = wm + mt * 16 + (quad << 2);
      const int sg  = m0 + rit;                 // global row in (B*S)
      const int b   = sg >> 12;
      const int s   = sg & 4095;
      const int npg = (s >> 8) & 15;
      const int half = (s >> 7) & 1;
      const int plo  = s & 127;                 // consecutive for the 4 regs
      const f32x4 v = acc[mt][nt];
      const size_t bb = ((size_t)((b * 16 + h) * 16 + npg)) << 15;  // *32768
      if (mode == 0) {
        U4 o = { f2bf(v[0] + bv), f2bf(v[1] + bv), f2bf(v[2] + bv), f2bf(v[3] + bv) };
        *(U4*)((u16*)outp + bb + (size_t)(2 * d + half) * 128 + plo) = o;
      } else if (mode == 1) {
        u16* o16 = (u16*)outp + bb + 2 * d + half;
        o16[(size_t)(plo + 0) * 256] = f2bf(v[0] + bv);
        o16[(size_t)(plo + 1) * 256] = f2bf(v[1] + bv);
        o16[(size_t)(plo + 2) * 256] = f2bf(v[2] + bv);
        o16[(size_t)(plo + 3) * 256] = f2bf(v[3] + bv);
      } else {
        float* of = (float*)outp + (size_t)sg * 2048 + c;
        of[0]    = v[0] + bv;
        of[2048] = v[1] + bv;
        of[4096] = v[2] + bv;
        of[6144] = v[3] + bv;
      }
    }
  }
}

// ---------------- Attention per paged block (register-only, no LDS) ----------------
// grid = 4096: pg = bid&1023 (x2*16+h2), qc = bid>>10 (64-query chunk).
// Each wave owns 16 queries. Computes S^T = K*Q^T so the softmax row is per-lane,
// then ctx^T = V^T * P^T; P^T B-frags built with shuffles from S^T C-frags.
__global__ __launch_bounds__(256) void attn_kernel(
    const u16* __restrict__ Qp, const u16* __restrict__ Kp,
    const u16* __restrict__ Vt, u16* __restrict__ ctx)
{
  const int tid  = threadIdx.x;
  const int wid  = tid >> 6;
  const int lane = tid & 63;
  const int L    = lane & 15;
  const int quad = lane >> 4;
  const int bid  = blockIdx.x;
  const int pg   = bid & 1023;
  const int qc   = bid >> 10;
  const int x2 = pg >> 4, h2 = pg & 15;
  const int q0 = qc * 64 + wid * 16;

  const char* Qb = (const char*)(Qp + (size_t)pg * 32768);
  const char* Kb = (const char*)(Kp + (size_t)pg * 32768);
  const char* Vb = (const char*)(Vt + (size_t)pg * 32768);

  // Q B-frags: B[k=d][n=q], lane holds Q[q0+L][kt*32+quad*8+j] (row-contiguous)
  bf16x8 qf[4];
#pragma unroll
  for (int kt = 0; kt < 4; ++kt)
    qf[kt] = *(const bf16x8*)(Qb + (q0 + L) * 256 + kt * 64 + quad * 16);

  // S^T accumulate: rows k2 (16 tiles), cols q (16). A = K rows (global, coalesced).
  f32x4 st[16];
#pragma unroll
  for (int mt = 0; mt < 16; ++mt) st[mt] = f32x4{0.f, 0.f, 0.f, 0.f};
#pragma unroll
  for (int mt = 0; mt < 16; ++mt) {
#pragma unroll
    for (int kt = 0; kt < 4; ++kt) {
      bf16x8 a = *(const bf16x8*)(Kb + (mt * 16 + L) * 256 + kt * 64 + quad * 16);
      st[mt] = __builtin_amdgcn_mfma_f32_16x16x32_bf16(a, qf[kt], st[mt], 0, 0, 0);
    }
  }

  // softmax over k2 for this lane's q (=L): 64 in-lane values + lanes {L,L+16,L+32,L+48}
  float mx = -3.0e38f;
#pragma unroll
  for (int mt = 0; mt < 16; ++mt) {
    mx = fmaxf(mx, st[mt][0]); mx = fmaxf(mx, st[mt][1]);
    mx = fmaxf(mx, st[mt][2]); mx = fmaxf(mx, st[mt][3]);
  }
  mx = fmaxf(mx, __shfl_xor(mx, 16));
  mx = fmaxf(mx, __shfl_xor(mx, 32));
  float sum = 0.f;
#pragma unroll
  for (int mt = 0; mt < 16; ++mt) {
#pragma unroll
    for (int r = 0; r < 4; ++r) {
      float e = __expf((st[mt][r] - mx) * SCALE_);
      st[mt][r] = e;
      sum += e;
    }
  }
  sum += __shfl_xor(sum, 16);
  sum += __shfl_xor(sum, 32);
  const float rinv = 1.f / sum;

  // ctx^T = V^T * P^T. A = VT rows (global). B frag: lane supplies P^T[kt*32+quad*8+j][L].
  f32x4 ct[8];
#pragma unroll
  for (int mt = 0; mt < 8; ++mt) ct[mt] = f32x4{0.f, 0.f, 0.f, 0.f};
#pragma unroll
  for (int kt = 0; kt < 8; ++kt) {
    u16x8 pt;
#pragma unroll
    for (int j = 0; j < 8; ++j) {
      // element k2 = kt*32 + quad*8 + j lives in C-frag 2kt+(quad>>1),
      // source lane = (2*(quad&1)+(j>>2))*16 + L, reg = j&3
      const int src = ((quad & 1) * 2 + (j >> 2)) * 16 + L;
      float v0 = __shfl(st[2 * kt][j & 3], src);
      float v1 = __shfl(st[2 * kt + 1][j & 3], src);
      pt[j] = f2bf(quad < 2 ? v0 : v1);
    }
    bf16x8 pb = __builtin_bit_cast(bf16x8, pt);
#pragma unroll
    for (int mt = 0; mt < 8; ++mt) {
      bf16x8 a = *(const bf16x8*)(Vb + (mt * 16 + L) * 512 + kt * 64 + quad * 16);
      ct[mt] = __builtin_amdgcn_mfma_f32_16x16x32_bf16(a, pb, ct[mt], 0, 0, 0);
    }
  }

  // Epilogue: ctx^T frag col = q (lane L), rows = d3. out[b][256h+q][128*h2+d3], bf16.
  const int b = x2 >> 4, h = x2 & 15;
  const int sg = h * 256 + q0 + L;
  u16* orow = ctx + ((size_t)b * 4096 + sg) * 2048 + h2 * 128;
#pragma unroll
  for (int mt = 0; mt < 8; ++mt) {
    U4 o = { f2bf(ct[mt][0] * rinv), f2bf(ct[mt][1] * rinv),
             f2bf(ct[mt][2] * rinv), f2bf(ct[mt][3] * rinv) };
    *(U4*)(orow + mt * 16 + quad * 4) = o;
  }
}

// ---------------- launch ----------------
extern "C" void kernel_launch(void* const* d_in, const int* in_sizes, int n_in,
                              void* d_out, int out_size, void* d_ws, size_t ws_size,
                              hipStream_t stream) {
  const float* X  = (const float*)d_in[0];
  const float* Wq = (const float*)d_in[1];
  const float* bq = (const float*)d_in[2];
  const float* Wk = (const float*)d_in[3];
  const float* bk = (const float*)d_in[4];
  const float* Wv = (const float*)d_in[5];
  const float* bv = (const float*)d_in[6];
  const float* Wo = (const float*)d_in[7];
  const float* bo = (const float*)d_in[8];

  char* ws = (char*)d_ws;
  u16* Xb  = (u16*)(ws);                    // 64 MB
  u16* Wqb = (u16*)(ws + 67108864);         // 8 MB each
  u16* Wkb = (u16*)(ws + 75497472);
  u16* Wvb = (u16*)(ws + 83886080);
  u16* Wob = (u16*)(ws + 92274688);
  u16* Qp  = (u16*)(ws + 100663296);        // 64 MB paged
  u16* Kp  = (u16*)(ws + 167772160);        // 64 MB paged
  u16* Vt  = (u16*)(ws + 234881024);        // 64 MB transposed-paged
  u16* Cb  = (u16*)(ws + 301989888);        // 64 MB ctx bf16 (B,S,HID)

  cvt_kernel<<<32768, 256, 0, stream>>>(X,  Xb,  8388608);
  cvt_kernel<<<4096,  256, 0, stream>>>(Wq, Wqb, 1048576);
  cvt_kernel<<<4096,  256, 0, stream>>>(Wk, Wkb, 1048576);
  cvt_kernel<<<4096,  256, 0, stream>>>(Wv, Wvb, 1048576);
  cvt_kernel<<<4096,  256, 0, stream>>>(Wo, Wob, 1048576);

  dim3 gg(16, 128);
  gemm_kernel<<<gg, 256, 0, stream>>>(Xb, Wqb, bq, (void*)Qp, 0);
  gemm_kernel<<<gg, 256, 0, stream>>>(Xb, Wkb, bk, (void*)Kp, 0);
  gemm_kernel<<<gg, 256, 0, stream>>>(Xb, Wvb, bv, (void*)Vt, 1);

  attn_kernel<<<4096, 256, 0, stream>>>(Qp, Kp, Vt, Cb);

  gemm_kernel<<<gg, 256, 0, stream>>>(Cb, Wob, bo, d_out, 2);
}

// Round 2
// 1141.605 us; speedup vs baseline: 1.2192x; 1.2192x over previous
//
#include <hip/hip_runtime.h>

// PagedAttention fused pipeline for MI355X (gfx950).
// B=4 S=4096 HID=2048 H=16 P=256 D=128 N=16.
// Paged permutation (derived from flat strides of the unfold/reshape):
//   q/k/v:  heads[b,h,n*P+p,d] -> paged[x2=16b+h][h2=n][p2=2d+(p>>7)][d2=p&127]
//   output: ctx[x2][h2][p2][d3] -> out[b=x2>>4][s=256*(x2&15)+p2][c=128*h2+d3]
// Pipeline: cvt fp32->bf16; QKV GEMMs (write paged / transposed-paged bf16);
// per-page MFMA attention (S^T orientation, K/V staged in LDS with XOR-swizzled
// chunk placement for conflict-free fragment reads); out-proj GEMM (fp32 out).

typedef unsigned short u16;
typedef unsigned int u32;
typedef __attribute__((ext_vector_type(8))) __bf16 bf16x8;
typedef __attribute__((ext_vector_type(4))) float f32x4;
typedef __attribute__((ext_vector_type(8))) u16 u16x8;

struct alignas(8) U4 { u16 x, y, z, w; };

#define SCALE_ 0.08838834764831845f

__device__ __forceinline__ u16 f2bf(float f) {
  union { float f; u32 u; } v; v.f = f;
  u32 r = v.u + 0x7fffu + ((v.u >> 16) & 1u);   // RNE
  return (u16)(r >> 16);
}

__device__ __forceinline__ void glds16(const void* g, void* l) {
  __builtin_amdgcn_global_load_lds(
      (const __attribute__((address_space(1))) u32*)g,
      (__attribute__((address_space(3))) u32*)l, 16, 0, 0);
}

// ---------------- fp32 -> bf16 conversion (vectorized x4) ----------------
__global__ void cvt_kernel(const float* __restrict__ src, u16* __restrict__ dst, int n4) {
  int i = blockIdx.x * 256 + threadIdx.x;
  if (i >= n4) return;
  float4 f = ((const float4*)src)[i];
  U4 o = { f2bf(f.x), f2bf(f.y), f2bf(f.z), f2bf(f.w) };
  ((U4*)dst)[i] = o;
}

// ---------------- GEMM: C[m,n] = sum_k A[m,k]*W[n,k] + bias[n] ----------------
// 128x128 tile, BK=32, 4 waves (2x2 of 64x64), global_load_lds staging.
// mode 0: write bf16 paged layout (Q/K).  mode 1: write bf16 transposed-paged (V).
// mode 2: write fp32 row-major (final output).
__global__ __launch_bounds__(256) void gemm_kernel(
    const u16* __restrict__ A, const u16* __restrict__ Bw,
    const float* __restrict__ bias, void* __restrict__ outp, int mode)
{
  __shared__ u16 As[128 * 32];
  __shared__ u16 Bs[128 * 32];
  const int tid  = threadIdx.x;
  const int wid  = tid >> 6;
  const int lane = tid & 63;
  const int L    = lane & 15;
  const int quad = lane >> 4;
  const int m0 = blockIdx.y << 7;
  const int n0 = blockIdx.x << 7;
  const int wm = (wid >> 1) << 6;
  const int wn = (wid & 1) << 6;

  f32x4 acc[4][4];
#pragma unroll
  for (int i = 0; i < 4; ++i)
#pragma unroll
    for (int j = 0; j < 4; ++j)
      acc[i][j] = f32x4{0.f, 0.f, 0.f, 0.f};

  for (int kk = 0; kk < 2048; kk += 32) {
#pragma unroll
    for (int r = 0; r < 2; ++r) {
      const int unit = tid + (r << 8);          // 0..511, 16B units
      const int row  = unit >> 2;               // 0..127
      const int su   = unit & 3;                // 0..3 (8 bf16 each)
      glds16(A  + (size_t)(m0 + row) * 2048 + kk + su * 8, (char*)As + unit * 16);
      glds16(Bw + (size_t)(n0 + row) * 2048 + kk + su * 8, (char*)Bs + unit * 16);
    }
    __syncthreads();
    bf16x8 af[4], bfr[4];
#pragma unroll
    for (int t = 0; t < 4; ++t) {
      af[t]  = *(const bf16x8*)((const char*)As + (wm + t * 16 + L) * 64 + quad * 16);
      bfr[t] = *(const bf16x8*)((const char*)Bs + (wn + t * 16 + L) * 64 + quad * 16);
    }
#pragma unroll
    for (int mt = 0; mt < 4; ++mt)
#pragma unroll
      for (int nt = 0; nt < 4; ++nt)
        acc[mt][nt] = __builtin_amdgcn_mfma_f32_16x16x32_bf16(af[mt], bfr[nt], acc[mt][nt], 0, 0, 0);
    __syncthreads();
  }

  // Epilogue. C frag: col = lane&15 (n), rows = quad*4 + reg (m).
#pragma unroll
  for (int nt = 0; nt < 4; ++nt) {
    const int c = n0 + wn + nt * 16 + L;
    const float bv = bias[c];
    const int h = c >> 7, d = c & 127;
#pragma unroll
    for (int mt = 0; mt < 4; ++mt) {
      const int rit = wm + mt * 16 + (quad << 2);
      const int sg  = m0 + rit;                 // global row in (B*S)
      const int b   = sg >> 12;
      const int s   = sg & 4095;
      const int npg = (s >> 8) & 15;
      const int half = (s >> 7) & 1;
      const int plo  = s & 127;                 // consecutive for the 4 regs
      const f32x4 v = acc[mt][nt];
      const size_t bb = ((size_t)((b * 16 + h) * 16 + npg)) << 15;  // *32768
      if (mode == 0) {
        U4 o = { f2bf(v[0] + bv), f2bf(v[1] + bv), f2bf(v[2] + bv), f2bf(v[3] + bv) };
        *(U4*)((u16*)outp + bb + (size_t)(2 * d + half) * 128 + plo) = o;
      } else if (mode == 1) {
        u16* o16 = (u16*)outp + bb + 2 * d + half;
        o16[(size_t)(plo + 0) * 256] = f2bf(v[0] + bv);
        o16[(size_t)(plo + 1) * 256] = f2bf(v[1] + bv);
        o16[(size_t)(plo + 2) * 256] = f2bf(v[2] + bv);
        o16[(size_t)(plo + 3) * 256] = f2bf(v[3] + bv);
      } else {
        float* of = (float*)outp + (size_t)sg * 2048 + c;
        of[0]    = v[0] + bv;
        of[2048] = v[1] + bv;
        of[4096] = v[2] + bv;
        of[6144] = v[3] + bv;
      }
    }
  }
}

// ---------------- Attention: one block (1024 thr, 16 waves) per page ----------------
// Stage K (64KB) into LDS with XOR-swizzled 16B-chunk placement (conflict-free
// fragment reads), compute S^T = K*Q^T, softmax in-register, then reuse the LDS
// for V and compute ctx^T = V^T * P^T (P^T B-frags built by shuffles).
__global__ __launch_bounds__(1024, 4) void attn_kernel(
    const u16* __restrict__ Qp, const u16* __restrict__ Kp,
    const u16* __restrict__ Vt, u16* __restrict__ ctx)
{
  __shared__ u16 Sm[32768];                    // 64 KB, holds K then V
  const int tid  = threadIdx.x;
  const int wid  = tid >> 6;
  const int lane = tid & 63;
  const int L    = lane & 15;
  const int quad = lane >> 4;
  const int pg   = blockIdx.x;                 // page = x2*16 + h2
  const int x2 = pg >> 4, h2 = pg & 15;
  const int q0 = wid * 16;                     // 16 queries per wave

  const char* Qb = (const char*)(Qp + (size_t)pg * 32768);
  const char* Kb = (const char*)(Kp + (size_t)pg * 32768);
  const char* Vb = (const char*)(Vt + (size_t)pg * 32768);

  // Stage K: LDS slot u (16B chunks): row=u>>4, cc=u&15; fetch global chunk
  // row*16 + (cc ^ (row&15)) so that K[row][c] lives at slot row*16 + (c^(row&15)).
#pragma unroll
  for (int r = 0; r < 4; ++r) {
    const int u = tid + (r << 10);
    const int row = u >> 4, cc = u & 15;
    glds16(Kb + (size_t)(row * 16 + (cc ^ (row & 15))) * 16, (char*)Sm + u * 16);
  }

  // Q B-frags: B[k=d][n=q], lane holds Q[q0+L][kt*32+quad*8+j] (row-contiguous)
  bf16x8 qf[4];
#pragma unroll
  for (int kt = 0; kt < 4; ++kt)
    qf[kt] = *(const bf16x8*)(Qb + (q0 + L) * 256 + kt * 64 + quad * 16);

  __syncthreads();

  // S^T accumulate: rows k2 (16 tiles), cols q (16). A = K rows from LDS.
  // Read K[row=mt*16+L][chunk c=kt*4+quad] at swizzled offset (c^L)*16.
  f32x4 st[16];
#pragma unroll
  for (int mt = 0; mt < 16; ++mt) st[mt] = f32x4{0.f, 0.f, 0.f, 0.f};
#pragma unroll
  for (int kt = 0; kt < 4; ++kt) {
    const int c = kt * 4 + quad;
#pragma unroll
    for (int mt = 0; mt < 16; ++mt) {
      bf16x8 a = *(const bf16x8*)((const char*)Sm + (mt * 16 + L) * 256 + ((c ^ L) << 4));
      st[mt] = __builtin_amdgcn_mfma_f32_16x16x32_bf16(a, qf[kt], st[mt], 0, 0, 0);
    }
  }

  // softmax over k2 for this lane's q (=L): 64 in-lane values + lanes {L,L+16,L+32,L+48}
  float mx = -3.0e38f;
#pragma unroll
  for (int mt = 0; mt < 16; ++mt) {
    mx = fmaxf(mx, st[mt][0]); mx = fmaxf(mx, st[mt][1]);
    mx = fmaxf(mx, st[mt][2]); mx = fmaxf(mx, st[mt][3]);
  }
  mx = fmaxf(mx, __shfl_xor(mx, 16));
  mx = fmaxf(mx, __shfl_xor(mx, 32));
  float sum = 0.f;
#pragma unroll
  for (int mt = 0; mt < 16; ++mt) {
#pragma unroll
    for (int r = 0; r < 4; ++r) {
      float e = __expf((st[mt][r] - mx) * SCALE_);
      st[mt][r] = e;
      sum += e;
    }
  }
  sum += __shfl_xor(sum, 16);
  sum += __shfl_xor(sum, 32);
  const float rinv = 1.f / sum;

  // All waves done reading K -> restage LDS with V (V^T page: 128 rows x 512B = 32 chunks).
  __syncthreads();
#pragma unroll
  for (int r = 0; r < 4; ++r) {
    const int u = tid + (r << 10);
    const int row = u >> 5, cc = u & 31;
    glds16(Vb + (size_t)(row * 32 + (cc ^ (row & 15))) * 16, (char*)Sm + u * 16);
  }
  __syncthreads();

  // ctx^T = V^T * P^T. A = V^T rows from LDS. B frag: lane supplies P^T[kt*32+quad*8+j][L].
  f32x4 ct[8];
#pragma unroll
  for (int mt = 0; mt < 8; ++mt) ct[mt] = f32x4{0.f, 0.f, 0.f, 0.f};
#pragma unroll
  for (int kt = 0; kt < 8; ++kt) {
    u16x8 pt;
#pragma unroll
    for (int j = 0; j < 8; ++j) {
      // element k2 = kt*32 + quad*8 + j lives in C-frag 2kt+(quad>>1),
      // source lane = (2*(quad&1)+(j>>2))*16 + L, reg = j&3
      const int src = ((quad & 1) * 2 + (j >> 2)) * 16 + L;
      float v0 = __shfl(st[2 * kt][j & 3], src);
      float v1 = __shfl(st[2 * kt + 1][j & 3], src);
      pt[j] = f2bf(quad < 2 ? v0 : v1);
    }
    bf16x8 pb = __builtin_bit_cast(bf16x8, pt);
    const int c = kt * 4 + quad;
#pragma unroll
    for (int mt = 0; mt < 8; ++mt) {
      bf16x8 a = *(const bf16x8*)((const char*)Sm + (mt * 16 + L) * 512 + ((c ^ L) << 4));
      ct[mt] = __builtin_amdgcn_mfma_f32_16x16x32_bf16(a, pb, ct[mt], 0, 0, 0);
    }
  }

  // Epilogue: ctx^T frag col = q (lane L), rows = d3. out[b][256h+q][128*h2+d3], bf16.
  const int b = x2 >> 4, h = x2 & 15;
  const int sg = h * 256 + q0 + L;
  u16* orow = ctx + ((size_t)b * 4096 + sg) * 2048 + h2 * 128;
#pragma unroll
  for (int mt = 0; mt < 8; ++mt) {
    U4 o = { f2bf(ct[mt][0] * rinv), f2bf(ct[mt][1] * rinv),
             f2bf(ct[mt][2] * rinv), f2bf(ct[mt][3] * rinv) };
    *(U4*)(orow + mt * 16 + quad * 4) = o;
  }
}

// ---------------- launch ----------------
extern "C" void kernel_launch(void* const* d_in, const int* in_sizes, int n_in,
                              void* d_out, int out_size, void* d_ws, size_t ws_size,
                              hipStream_t stream) {
  const float* X  = (const float*)d_in[0];
  const float* Wq = (const float*)d_in[1];
  const float* bq = (const float*)d_in[2];
  const float* Wk = (const float*)d_in[3];
  const float* bk = (const float*)d_in[4];
  const float* Wv = (const float*)d_in[5];
  const float* bv = (const float*)d_in[6];
  const float* Wo = (const float*)d_in[7];
  const float* bo = (const float*)d_in[8];

  char* ws = (char*)d_ws;
  u16* Xb  = (u16*)(ws);                    // 64 MB
  u16* Wqb = (u16*)(ws + 67108864);         // 8 MB each
  u16* Wkb = (u16*)(ws + 75497472);
  u16* Wvb = (u16*)(ws + 83886080);
  u16* Wob = (u16*)(ws + 92274688);
  u16* Qp  = (u16*)(ws + 100663296);        // 64 MB paged
  u16* Kp  = (u16*)(ws + 167772160);        // 64 MB paged
  u16* Vt  = (u16*)(ws + 234881024);        // 64 MB transposed-paged
  u16* Cb  = (u16*)(ws + 301989888);        // 64 MB ctx bf16 (B,S,HID)

  cvt_kernel<<<32768, 256, 0, stream>>>(X,  Xb,  8388608);
  cvt_kernel<<<4096,  256, 0, stream>>>(Wq, Wqb, 1048576);
  cvt_kernel<<<4096,  256, 0, stream>>>(Wk, Wkb, 1048576);
  cvt_kernel<<<4096,  256, 0, stream>>>(Wv, Wvb, 1048576);
  cvt_kernel<<<4096,  256, 0, stream>>>(Wo, Wob, 1048576);

  dim3 gg(16, 128);
  gemm_kernel<<<gg, 256, 0, stream>>>(Xb, Wqb, bq, (void*)Qp, 0);
  gemm_kernel<<<gg, 256, 0, stream>>>(Xb, Wkb, bk, (void*)Kp, 0);
  gemm_kernel<<<gg, 256, 0, stream>>>(Xb, Wvb, bv, (void*)Vt, 1);

  attn_kernel<<<1024, 1024, 0, stream>>>(Qp, Kp, Vt, Cb);

  gemm_kernel<<<gg, 256, 0, stream>>>(Cb, Wob, bo, d_out, 2);
}